// Round 6
// baseline (106.830 us; speedup 1.0000x reference)
//
#include <hip/hip_runtime.h>

// Problem constants (fixed by reference file).
#define BQ    1000000
#define SPIN  10000
#define TRAIN 800000
#define NOBS  (TRAIN - SPIN)          // 790000
#define CHUNK 9                       // odd -> stride-9 LDS is conflict-free
#define BLK_ELEMS (64 * CHUNK)        // 576 elements per block
#define NBLK 1737                     // 1737*576 = 1,000,512 >= BQ
#define LOOKBACK 64                   // absmax identical at 320/192/128: floor
                                      // is approx error; 64-step contraction
                                      // bound still ~1e-8 of |c|
#define XWIN (LOOKBACK + BLK_ELEMS)   // 640 = 5 * 128 (exact staging)
#define RED_BLOCKS 64

typedef float vf4 __attribute__((ext_vector_type(4)));  // native vector for
                                                        // nontemporal builtins

// ---------------------------------------------------------------------------
// Kernel 1: per-block partial sum/sumsq of y_obs[SPIN:TRAIN] (double, float4).
// Deterministic, no atomics, every ws slot written (ws is poisoned).
// ---------------------------------------------------------------------------
__global__ __launch_bounds__(256) void std_partials_kernel(
    const float* __restrict__ y, double* __restrict__ ws) {
  const float4* y4 = (const float4*)(y + SPIN);   // 40000 B offset, 16-aligned
  const int NG = NOBS / 4;                        // 197500
  int tid = blockIdx.x * 256 + threadIdx.x;
  double s = 0.0, ss = 0.0;
  for (int g = tid; g < NG; g += RED_BLOCKS * 256) {
    float4 v = y4[g];
    double a = v.x, b = v.y, c = v.z, d = v.w;
    s += (a + b) + (c + d);
    ss += (a * a + b * b) + (c * c + d * d);
  }
  for (int off = 32; off > 0; off >>= 1) {
    s  += __shfl_down(s, off);
    ss += __shfl_down(ss, off);
  }
  __shared__ double sm[4][2];
  int wave = threadIdx.x >> 6;
  if ((threadIdx.x & 63) == 0) { sm[wave][0] = s; sm[wave][1] = ss; }
  __syncthreads();
  if (threadIdx.x == 0) {
    ws[2 * blockIdx.x]     = sm[0][0] + sm[1][0] + sm[2][0] + sm[3][0];
    ws[2 * blockIdx.x + 1] = sm[0][1] + sm[1][1] + sm[2][1] + sm[3][1];
  }
}

// ---------------------------------------------------------------------------
// Kernel 2: chunked speculative scan.
//   Stage:   x window [R-64, R+576) -> LDS; precompute per-element
//            g = 1 - ol1*sigmoid(b0l + w2*u.y)  (ol-gate is carry-independent)
//   Phase A: per-lane serial carry chain c <- c*(g - oo1*r1(c)) + u.x,
//            conflict-free LDS (odd stride 9), staging pre-update c into cbuf.
//   Phase B: block-coalesced nontemporal float4 flush of all 11 streams
//            (ol = 1-g, f = g-oo come free from staged g).
// ---------------------------------------------------------------------------
__global__ __launch_bounds__(64) void scan_kernel(
    const float2* __restrict__ x,
    const float* __restrict__ wr_yom, const float* __restrict__ wr_ylm,
    const float* __restrict__ wr_yfm, const float* __restrict__ b0_yom,
    const float* __restrict__ wb1_yom, const float* __restrict__ b0_ylm,
    const float* __restrict__ wb2_ylm,
    const double* __restrict__ ws, float* __restrict__ out) {
  __shared__ __align__(16) float xs[XWIN];      // u.x window
  __shared__ __align__(16) float gs[XWIN];      // g = 1 - ol (precomputed)
  __shared__ __align__(16) float cbuf[BLK_ELEMS];
  const int l = threadIdx.x;
  const int R = blockIdx.x * BLK_ELEMS;

  // --- scalar gate parameters (H=1) ---
  float eo = __expf(wr_yom[0]);
  float el = __expf(wr_ylm[0]);
  float ef = __expf(wr_yfm[0]);
  float denom = eo + el + ef;
  float oo1 = eo / denom;
  float ol1 = el / denom;
  const float K2E = 1.44269504088896340736f;
  float a1 = -wb1_yom[0] * K2E, k1 = -b0_yom[0] * K2E;   // oo-gate arg
  float a2 = -wb2_ylm[0] * K2E, k2 = -b0_ylm[0] * K2E;   // ol-gate arg

  // --- stage x window into LDS; fuse ol-sigmoid precompute (5 exact passes) --
  const int gbase = R - LOOKBACK;
#pragma unroll
  for (int k = 0; k < XWIN / 128; ++k) {
    int e = (k * 64 + l) * 2;                 // even element index in window
    int g = gbase + e;
    float2 v0, v1;
    if (g >= 0 && g + 1 < BQ) {
      float4 v = *(const float4*)&x[g];       // g even -> 16B aligned
      v0 = make_float2(v.x, v.y); v1 = make_float2(v.z, v.w);
    } else {
      v0 = (g >= 0 && g < BQ) ? x[g] : make_float2(0.0f, 0.0f);
      v1 = (g + 1 >= 0 && g + 1 < BQ) ? x[g + 1] : make_float2(0.0f, 0.0f);
    }
    xs[e]     = v0.x;
    xs[e + 1] = v1.x;
    gs[e]     = fmaf(-ol1, __builtin_amdgcn_rcpf(
        1.0f + __builtin_amdgcn_exp2f(fmaf(v0.y, a2, k2))), 1.0f);
    gs[e + 1] = fmaf(-ol1, __builtin_amdgcn_rcpf(
        1.0f + __builtin_amdgcn_exp2f(fmaf(v1.y, a2, k2))), 1.0f);
  }

  // --- reduce 64 std partials across the wave while staging lands ---
  double S  = ws[2 * l];
  double SS = ws[2 * l + 1];
  for (int off = 32; off > 0; off >>= 1) {
    S  += __shfl_xor(S, off);
    SS += __shfl_xor(SS, off);
  }
  const float stdv =
      (float)sqrt((SS - S * S / (double)NOBS) / (double)(NOBS - 1));

  __syncthreads();

  // --- Phase A: serial carry chain from LDS ---
  const int s0 = R + CHUNK * l;
  if (s0 < BQ) {
    const int wsteps = min(LOOKBACK, s0);
    const int nmain = min(CHUNK, BQ - s0);
    float c = 0.0f;
    int idx = CHUNK * l + (LOOKBACK - wsteps);

    // c1 = c*(g - oo1*r1) + ux = fma(c,g,ux) - (oo1*c)*r1
#define STEP()                                                        \
    do {                                                              \
      float ux = xs[idx], gg = gs[idx];                               \
      float r1 = __builtin_amdgcn_rcpf(                               \
          1.0f + __builtin_amdgcn_exp2f(fmaf(c, a1, k1)));            \
      float t = oo1 * c;                                              \
      float p = fmaf(c, gg, ux);                                      \
      c = fmaf(-t, r1, p);                                            \
      ++idx;                                                          \
    } while (0)

    if (wsteps == LOOKBACK && nmain == CHUNK) {    // hot path: fixed trips
#pragma unroll 8
      for (int t = 0; t < LOOKBACK; ++t) STEP();
#pragma unroll
      for (int t = 0; t < CHUNK; ++t) { cbuf[CHUNK * l + t] = c; STEP(); }
    } else {
      for (int t = 0; t < wsteps; ++t) STEP();
      for (int t = 0; t < nmain; ++t) { cbuf[CHUNK * l + t] = c; STEP(); }
    }
#undef STEP
  }
  __syncthreads();

  // --- Phase B: coalesced nontemporal flush, 4 elements / lane-iteration ---
  const int ng = min(BLK_ELEMS, BQ - R) >> 2;   // tail (64) is %4==0
  const vf4 z4 = {0.0f, 0.0f, 0.0f, 0.0f};
  for (int i = l; i < ng; i += 64) {
    const int b0 = R + 4 * i;
    vf4 c4 = *(const vf4*)&cbuf[4 * i];
    vf4 g4 = *(const vf4*)&gs[LOOKBACK + 4 * i];
    vf4 hv, lv, oov, olv, fv;
#pragma unroll
    for (int e = 0; e < 4; ++e) {
      float ce = c4[e];
      float oo_ = oo1 * __builtin_amdgcn_rcpf(
          1.0f + __builtin_amdgcn_exp2f(fmaf(ce, a1, k1)));
      float ol_ = 1.0f - g4[e];
      hv[e] = oo_ * ce; lv[e] = ol_ * ce;
      oov[e] = oo_; olv[e] = ol_; fv[e] = g4[e] - oo_;
    }
    vf4 s4 = {stdv, stdv, stdv, stdv};
    vf4 hs0 = {hv[0], stdv, hv[1], stdv};
    vf4 hs1 = {hv[2], stdv, hv[3], stdv};
#define NTS(p, v) __builtin_nontemporal_store((v), (vf4*)(p))
    NTS(out + b0,          hv);
    NTS(out + BQ + b0,     c4);
    NTS(out + 2 * BQ + b0, lv);
    NTS(out + 3 * BQ + b0, z4);
    NTS(out + 4 * BQ + b0, z4);
    NTS(out + 5 * BQ + b0, oov);
    NTS(out + 6 * BQ + b0, olv);
    NTS(out + 7 * BQ + b0, fv);
    NTS(out + 8 * BQ + 2 * b0,     hs0);
    NTS(out + 8 * BQ + 2 * b0 + 4, hs1);
    NTS(out + 10 * BQ + b0, s4);
#undef NTS
  }
}

extern "C" void kernel_launch(void* const* d_in, const int* in_sizes, int n_in,
                              void* d_out, int out_size, void* d_ws, size_t ws_size,
                              hipStream_t stream) {
  const float* x       = (const float*)d_in[0];
  const float* y_obs   = (const float*)d_in[1];
  const float* wr_yom  = (const float*)d_in[2];
  const float* wr_ylm  = (const float*)d_in[3];
  const float* wr_yfm  = (const float*)d_in[4];
  const float* b0_yom  = (const float*)d_in[5];
  const float* wb1_yom = (const float*)d_in[6];
  const float* b0_ylm  = (const float*)d_in[7];
  const float* wb2_ylm = (const float*)d_in[8];
  float* out = (float*)d_out;
  double* ws = (double*)d_ws;

  std_partials_kernel<<<RED_BLOCKS, 256, 0, stream>>>(y_obs, ws);

  scan_kernel<<<NBLK, 64, 0, stream>>>(
      (const float2*)x, wr_yom, wr_ylm, wr_yfm, b0_yom, wb1_yom, b0_ylm,
      wb2_ylm, ws, out);
}

// Round 7
// 102.520 us; speedup vs baseline: 1.0420x; 1.0420x over previous
//
#include <hip/hip_runtime.h>

// Problem constants (fixed by reference file).
#define BQ    1000000
#define SPIN  10000
#define TRAIN 800000
#define NOBS  (TRAIN - SPIN)          // 790000
#define CHUNK 17                      // coprime with 32 -> conflict-free LDS
#define BLK_ELEMS (64 * CHUNK)        // 1088 elements per block
#define NBLK 920                      // 920*1088 = 1,000,960 >= BQ
#define LOOKBACK 128                  // contraction bound 0.923^128*|c| ~ 7e-4
#define XWIN (LOOKBACK + BLK_ELEMS)   // 1216
#define RED_BLOCKS 256

// ---------------------------------------------------------------------------
// Kernel 1: per-block partial sum/sumsq of y_obs[SPIN:TRAIN] (double, float4).
// Deterministic, no atomics, every ws slot written (ws is poisoned).
// ---------------------------------------------------------------------------
__global__ __launch_bounds__(256) void std_partials_kernel(
    const float* __restrict__ y, double* __restrict__ ws) {
  const float4* y4 = (const float4*)(y + SPIN);   // 40000 B offset, 16-aligned
  const int NG = NOBS / 4;                        // 197500
  int tid = blockIdx.x * 256 + threadIdx.x;
  double s = 0.0, ss = 0.0;
  for (int g = tid; g < NG; g += RED_BLOCKS * 256) {
    float4 v = y4[g];
    double a = v.x, b = v.y, c = v.z, d = v.w;
    s += (a + b) + (c + d);
    ss += (a * a + b * b) + (c * c + d * d);
  }
  for (int off = 32; off > 0; off >>= 1) {
    s  += __shfl_down(s, off);
    ss += __shfl_down(ss, off);
  }
  __shared__ double sm[4][2];
  int wave = threadIdx.x >> 6;
  if ((threadIdx.x & 63) == 0) { sm[wave][0] = s; sm[wave][1] = ss; }
  __syncthreads();
  if (threadIdx.x == 0) {
    ws[2 * blockIdx.x]     = sm[0][0] + sm[1][0] + sm[2][0] + sm[3][0];
    ws[2 * blockIdx.x + 1] = sm[0][1] + sm[1][1] + sm[2][1] + sm[3][1];
  }
}

// ---------------------------------------------------------------------------
// Kernel 2: chunked speculative scan.
//   Stage:   x window [R-128, R+1088) -> LDS; precompute per-element
//            g = 1 - ol1*sigmoid(b0l + w2*u.y)  (ol-gate is carry-independent!)
//   Phase A: per-lane serial carry chain c <- c*(g - oo1*r1(c)) + u.x,
//            conflict-free LDS (stride 17), staging pre-update c into cbuf.
//   Phase B: block-coalesced float4 recompute+flush of all 11 output streams
//            (ol = 1-g, f = g-oo come free from staged g).
// ---------------------------------------------------------------------------
__global__ __launch_bounds__(64) void scan_kernel(
    const float2* __restrict__ x,
    const float* __restrict__ wr_yom, const float* __restrict__ wr_ylm,
    const float* __restrict__ wr_yfm, const float* __restrict__ b0_yom,
    const float* __restrict__ wb1_yom, const float* __restrict__ b0_ylm,
    const float* __restrict__ wb2_ylm,
    const double* __restrict__ ws, float* __restrict__ out) {
  __shared__ __align__(16) float xs[XWIN];      // u.x window
  __shared__ __align__(16) float gs[XWIN];      // g = 1 - ol (precomputed)
  __shared__ __align__(16) float cbuf[BLK_ELEMS];
  const int l = threadIdx.x;
  const int R = blockIdx.x * BLK_ELEMS;

  // --- scalar gate parameters (H=1) ---
  float eo = __expf(wr_yom[0]);
  float el = __expf(wr_ylm[0]);
  float ef = __expf(wr_yfm[0]);
  float denom = eo + el + ef;
  float oo1 = eo / denom;
  float ol1 = el / denom;
  const float K2E = 1.44269504088896340736f;
  float a1 = -wb1_yom[0] * K2E, k1 = -b0_yom[0] * K2E;   // oo-gate arg
  float a2 = -wb2_ylm[0] * K2E, k2 = -b0_ylm[0] * K2E;   // ol-gate arg

  // --- stage x window into LDS; fuse ol-sigmoid precompute ---
  const int gbase = R - LOOKBACK;
#pragma unroll
  for (int k = 0; k < (XWIN + 127) / 128; ++k) {
    int e = (k * 64 + l) * 2;                 // even element index in window
    if (e >= XWIN) break;
    int g = gbase + e;
    float2 v0, v1;
    if (g >= 0 && g + 1 < BQ) {
      float4 v = *(const float4*)&x[g];       // g even -> 16B aligned
      v0 = make_float2(v.x, v.y); v1 = make_float2(v.z, v.w);
    } else {
      v0 = (g >= 0 && g < BQ) ? x[g] : make_float2(0.0f, 0.0f);
      v1 = (g + 1 >= 0 && g + 1 < BQ) ? x[g + 1] : make_float2(0.0f, 0.0f);
    }
    xs[e]     = v0.x;
    xs[e + 1] = v1.x;
    gs[e]     = fmaf(-ol1, __builtin_amdgcn_rcpf(
        1.0f + __builtin_amdgcn_exp2f(fmaf(v0.y, a2, k2))), 1.0f);
    gs[e + 1] = fmaf(-ol1, __builtin_amdgcn_rcpf(
        1.0f + __builtin_amdgcn_exp2f(fmaf(v1.y, a2, k2))), 1.0f);
  }

  // --- reduce 256 std partials across the wave while staging lands ---
  double S = 0.0, SS = 0.0;
#pragma unroll
  for (int k = 0; k < 4; ++k) {
    S  += ws[2 * (l + 64 * k)];
    SS += ws[2 * (l + 64 * k) + 1];
  }
  for (int off = 32; off > 0; off >>= 1) {
    S  += __shfl_xor(S, off);
    SS += __shfl_xor(SS, off);
  }
  const float stdv =
      (float)sqrt((SS - S * S / (double)NOBS) / (double)(NOBS - 1));

  __syncthreads();

  // --- Phase A: serial carry chain from LDS ---
  const int s0 = R + CHUNK * l;
  if (s0 < BQ) {
    const int wsteps = min(LOOKBACK, s0);
    const int nmain = min(CHUNK, BQ - s0);
    float c = 0.0f;
    int idx = CHUNK * l + (LOOKBACK - wsteps);

    // c1 = c*(g - oo1*r1) + ux = fma(c,g,ux) - (oo1*c)*r1
#define STEP()                                                        \
    do {                                                              \
      float ux = xs[idx], gg = gs[idx];                               \
      float r1 = __builtin_amdgcn_rcpf(                               \
          1.0f + __builtin_amdgcn_exp2f(fmaf(c, a1, k1)));            \
      float t = oo1 * c;                                              \
      float p = fmaf(c, gg, ux);                                      \
      c = fmaf(-t, r1, p);                                            \
      ++idx;                                                          \
    } while (0)

    if (wsteps == LOOKBACK && nmain == CHUNK) {    // hot path: fixed trips
#pragma unroll 8
      for (int t = 0; t < LOOKBACK; ++t) STEP();
#pragma unroll
      for (int t = 0; t < CHUNK; ++t) { cbuf[CHUNK * l + t] = c; STEP(); }
    } else {
      for (int t = 0; t < wsteps; ++t) STEP();
      for (int t = 0; t < nmain; ++t) { cbuf[CHUNK * l + t] = c; STEP(); }
    }
#undef STEP
  }
  __syncthreads();

  // --- Phase B: coalesced flush, 4 elements / lane-iteration ---
  const int ng = min(BLK_ELEMS, BQ - R) >> 2;   // groups of 4 (always %4==0)
  const float4 z4 = {0.0f, 0.0f, 0.0f, 0.0f};
  const float4 s4 = {stdv, stdv, stdv, stdv};
  for (int i = l; i < ng; i += 64) {
    const int b0 = R + 4 * i;
    float4 c4 = *(const float4*)&cbuf[4 * i];
    float4 g4 = *(const float4*)&gs[LOOKBACK + 4 * i];
    float cc[4] = {c4.x, c4.y, c4.z, c4.w};
    float gg[4] = {g4.x, g4.y, g4.z, g4.w};
    float hv[4], lv[4], oov[4], olv[4], fv[4];
#pragma unroll
    for (int e = 0; e < 4; ++e) {
      float ce = cc[e];
      float oo_ = oo1 * __builtin_amdgcn_rcpf(
          1.0f + __builtin_amdgcn_exp2f(fmaf(ce, a1, k1)));
      float ol_ = 1.0f - gg[e];
      hv[e] = oo_ * ce; lv[e] = ol_ * ce;
      oov[e] = oo_; olv[e] = ol_; fv[e] = gg[e] - oo_;
    }
    *(float4*)(out + b0)          = make_float4(hv[0], hv[1], hv[2], hv[3]);
    *(float4*)(out + BQ + b0)     = c4;
    *(float4*)(out + 2 * BQ + b0) = make_float4(lv[0], lv[1], lv[2], lv[3]);
    *(float4*)(out + 3 * BQ + b0) = z4;
    *(float4*)(out + 4 * BQ + b0) = z4;
    *(float4*)(out + 5 * BQ + b0) = make_float4(oov[0], oov[1], oov[2], oov[3]);
    *(float4*)(out + 6 * BQ + b0) = make_float4(olv[0], olv[1], olv[2], olv[3]);
    *(float4*)(out + 7 * BQ + b0) = make_float4(fv[0], fv[1], fv[2], fv[3]);
    *(float4*)(out + 8 * BQ + 2 * b0)     = make_float4(hv[0], stdv, hv[1], stdv);
    *(float4*)(out + 8 * BQ + 2 * b0 + 4) = make_float4(hv[2], stdv, hv[3], stdv);
    *(float4*)(out + 10 * BQ + b0) = s4;
  }
}

extern "C" void kernel_launch(void* const* d_in, const int* in_sizes, int n_in,
                              void* d_out, int out_size, void* d_ws, size_t ws_size,
                              hipStream_t stream) {
  const float* x       = (const float*)d_in[0];
  const float* y_obs   = (const float*)d_in[1];
  const float* wr_yom  = (const float*)d_in[2];
  const float* wr_ylm  = (const float*)d_in[3];
  const float* wr_yfm  = (const float*)d_in[4];
  const float* b0_yom  = (const float*)d_in[5];
  const float* wb1_yom = (const float*)d_in[6];
  const float* b0_ylm  = (const float*)d_in[7];
  const float* wb2_ylm = (const float*)d_in[8];
  float* out = (float*)d_out;
  double* ws = (double*)d_ws;

  std_partials_kernel<<<RED_BLOCKS, 256, 0, stream>>>(y_obs, ws);

  scan_kernel<<<NBLK, 64, 0, stream>>>(
      (const float2*)x, wr_yom, wr_ylm, wr_yfm, b0_yom, wb1_yom, b0_ylm,
      wb2_ylm, ws, out);
}